// Round 9
// baseline (313.676 us; speedup 1.0000x reference)
//
#include <hip/hip_runtime.h>
#include <math.h>

#define NVEC 131072
#define DIM 64
#define KCB 512
#define FLT_BIG 3.402823466e38f

typedef __attribute__((ext_vector_type(8))) short bf16x8;
typedef __attribute__((ext_vector_type(4))) float f32x4;

// d_out layout (floats): [0] loss | [1..8388608] quantized | [8388609] perplexity
//                        | [8388610 ..] encodings (131072 x 512)
// d_ws layout (bytes):
//   [0,2048)         u32 counts[512]
//   [2048]           float loss_acc
//   [2052]           u32 done (block completion ticket)
//   [4096,6144)      float norms[512]
//   [8192, +128K)    ushort e_bf[512][128]      (row: eh[64] | el[64])

__device__ inline unsigned int bf16_rne(float f) {
    unsigned int u = __float_as_uint(f);
    u += 0x7fffu + ((u >> 16) & 1u);
    return u >> 16;
}

__device__ inline void split_frag(float4 p0, float4 p1, bf16x8& hi, bf16x8& lo) {
    union { bf16x8 v; unsigned int u[4]; } H, L;
    float f[8] = {p0.x, p0.y, p0.z, p0.w, p1.x, p1.y, p1.z, p1.w};
    unsigned int h[8];
    float r[8];
#pragma unroll
    for (int j = 0; j < 8; ++j) {
        h[j] = bf16_rne(f[j]);
        r[j] = f[j] - __uint_as_float(h[j] << 16);
    }
#pragma unroll
    for (int j = 0; j < 4; ++j) {
        H.u[j] = h[2 * j] | (h[2 * j + 1] << 16);
        L.u[j] = bf16_rne(r[2 * j]) | (bf16_rne(r[2 * j + 1]) << 16);
    }
    hi = H.v;
    lo = L.v;
}

// merge two top-2 lists across lane groups (k-subsets are disjoint)
__device__ inline void merge_top2(float& d1, int& i1, float& d2, int& i2) {
#pragma unroll
    for (int m = 16; m <= 32; m <<= 1) {
        float e1 = __shfl_xor(d1, m), e2 = __shfl_xor(d2, m);
        int j1 = __shfl_xor(i1, m), j2 = __shfl_xor(i2, m);
        bool af = (d1 < e1) || (d1 == e1 && i1 < j1);
        float w2 = af ? d2 : e2; int w2i = af ? i2 : j2;   // winner's runner-up
        float lb = af ? e1 : d1; int lbi = af ? j1 : i1;   // loser's best
        bool bs = (w2 < lb) || (w2 == lb && w2i < lbi);
        d1 = af ? d1 : e1; i1 = af ? i1 : j1;
        d2 = bs ? w2 : lb; i2 = bs ? w2i : lbi;
    }
}

// prep: norms (fp32), bf16 hi/lo codebook, zero counts/loss/done
__global__ __launch_bounds__(256) void vq_prep(const float* __restrict__ emb,
                                               float* __restrict__ norms,
                                               unsigned short* __restrict__ e_bf,
                                               unsigned int* __restrict__ counts,
                                               float* __restrict__ loss_acc,
                                               unsigned int* __restrict__ done) {
    int gid = blockIdx.x * 256 + threadIdx.x;   // 0..2047
    int row = gid >> 2, part = gid & 3, d0 = part * 16;
    const float* e = emb + row * DIM + d0;
    float s = 0.f;
#pragma unroll
    for (int d = 0; d < 16; ++d) s = fmaf(e[d], e[d], s);
    s += __shfl_xor(s, 1);
    s += __shfl_xor(s, 2);
    if (part == 0) norms[row] = s;
#pragma unroll
    for (int d = 0; d < 16; ++d) {
        float f = e[d];
        unsigned int h = bf16_rne(f);
        float r = f - __uint_as_float(h << 16);
        e_bf[row * 128 + d0 + d] = (unsigned short)h;
        e_bf[row * 128 + 64 + d0 + d] = (unsigned short)bf16_rne(r);
    }
    if (gid < KCB) counts[gid] = 0u;
    if (gid == 0) { *loss_acc = 0.f; *done = 0u; }
}

// fused: MFMA top-2 argmin, exact fp32 rescore, loss, histogram,
// quantized + one-hot writes, last-block finalization of loss/perplexity.
// (encodings region pre-zeroed by hipMemsetAsync on the stream)
__global__ __launch_bounds__(256) void vq_fused(const float* __restrict__ x,
                                                const float* __restrict__ emb,
                                                const unsigned short* __restrict__ e_bf,
                                                const float* __restrict__ norms,
                                                float* __restrict__ out,
                                                unsigned int* __restrict__ counts,
                                                float* __restrict__ loss_acc,
                                                unsigned int* __restrict__ done) {
    float* __restrict__ qout = out + 1;
    float* __restrict__ enc  = out + 8388610;
    int tid = threadIdx.x;
    int wave = tid >> 6;
    int lane = tid & 63;
    int nl = lane & 15, kg = lane >> 4;
    int rowA = blockIdx.x * 128 + wave * 32 + nl;
    int rowB = rowA + 16;

    __shared__ unsigned int hist[KCB];
    __shared__ int2 scand[128];
    __shared__ int sbi[128];
    __shared__ float serr[128];
    __shared__ unsigned int ticket_s;
    for (int j = tid; j < KCB; j += 256) hist[j] = 0u;

    // B-frags (x side): lane col = x-row, k = kg*8+e (+32 per kslice)
    bf16x8 xhA[2], xlA[2], xhB[2], xlB[2];
    {
        const float* xA = x + (size_t)rowA * DIM;
        const float* xB = x + (size_t)rowB * DIM;
#pragma unroll
        for (int ks = 0; ks < 2; ++ks) {
            const float4* pA = (const float4*)(xA + ks * 32 + kg * 8);
            const float4* pB = (const float4*)(xB + ks * 32 + kg * 8);
            split_frag(pA[0], pA[1], xhA[ks], xlA[ks]);
            split_frag(pB[0], pB[1], xhB[ks], xlB[ks]);
        }
    }

    float d1A = FLT_BIG, d2A = FLT_BIG, d1B = FLT_BIG, d2B = FLT_BIG;
    int i1A = 0, i2A = 0, i1B = 0, i2B = 0;

    const unsigned short* ebl = e_bf + (size_t)nl * 128;
#pragma unroll 2
    for (int t = 0; t < 32; ++t) {
        const unsigned short* eb = ebl + t * 2048;  // codebook row t*16+nl
        bf16x8 eh0 = *(const bf16x8*)(eb + kg * 8);
        bf16x8 eh1 = *(const bf16x8*)(eb + 32 + kg * 8);
        bf16x8 el0 = *(const bf16x8*)(eb + 64 + kg * 8);
        bf16x8 el1 = *(const bf16x8*)(eb + 96 + kg * 8);

        f32x4 aA = {}, aB = {};
        // dot = xh*eh + xh*el + xl*eh  (A = e-side, B = x-side)
        aA = __builtin_amdgcn_mfma_f32_16x16x32_bf16(eh0, xhA[0], aA, 0, 0, 0);
        aA = __builtin_amdgcn_mfma_f32_16x16x32_bf16(eh1, xhA[1], aA, 0, 0, 0);
        aA = __builtin_amdgcn_mfma_f32_16x16x32_bf16(el0, xhA[0], aA, 0, 0, 0);
        aA = __builtin_amdgcn_mfma_f32_16x16x32_bf16(el1, xhA[1], aA, 0, 0, 0);
        aA = __builtin_amdgcn_mfma_f32_16x16x32_bf16(eh0, xlA[0], aA, 0, 0, 0);
        aA = __builtin_amdgcn_mfma_f32_16x16x32_bf16(eh1, xlA[1], aA, 0, 0, 0);

        aB = __builtin_amdgcn_mfma_f32_16x16x32_bf16(eh0, xhB[0], aB, 0, 0, 0);
        aB = __builtin_amdgcn_mfma_f32_16x16x32_bf16(eh1, xhB[1], aB, 0, 0, 0);
        aB = __builtin_amdgcn_mfma_f32_16x16x32_bf16(el0, xhB[0], aB, 0, 0, 0);
        aB = __builtin_amdgcn_mfma_f32_16x16x32_bf16(el1, xhB[1], aB, 0, 0, 0);
        aB = __builtin_amdgcn_mfma_f32_16x16x32_bf16(eh0, xlB[0], aB, 0, 0, 0);
        aB = __builtin_amdgcn_mfma_f32_16x16x32_bf16(eh1, xlB[1], aB, 0, 0, 0);

        // C/D: col=lane&15 (x-row), row=(lane>>4)*4+reg (e-idx) [m89-verified]
        int krow0 = t * 16 + kg * 4;
#pragma unroll
        for (int r = 0; r < 4; ++r) {
            float en = norms[krow0 + r];
            int ki = krow0 + r;
            float dA = fmaf(-2.f, aA[r], en);   // xn dropped: row-constant
            bool c1 = dA < d1A, c2 = dA < d2A;
            d2A = c1 ? d1A : (c2 ? dA : d2A);
            i2A = c1 ? i1A : (c2 ? ki : i2A);
            d1A = c1 ? dA : d1A;
            i1A = c1 ? ki : i1A;
            float dB = fmaf(-2.f, aB[r], en);
            bool e1c = dB < d1B, e2c = dB < d2B;
            d2B = e1c ? d1B : (e2c ? dB : d2B);
            i2B = e1c ? i1B : (e2c ? ki : i2B);
            d1B = e1c ? dB : d1B;
            i1B = e1c ? ki : i1B;
        }
    }

    merge_top2(d1A, i1A, d2A, i2A);
    merge_top2(d1B, i1B, d2B, i2B);
    if (lane < 16) {
        scand[wave * 32 + nl] = make_int2(i1A, i2A);
        scand[wave * 32 + nl + 16] = make_int2(i1B, i2B);
    }
    __syncthreads();

    // ---- exact fp32 rescore: one thread per row, STREAMED (low VGPR)
    if (tid < 128) {
        int grow = blockIdx.x * 128 + tid;
        int2 cd = scand[tid];
        const float4* xr = (const float4*)(x + (size_t)grow * DIM);
        const float4* eA = (const float4*)(emb + (size_t)cd.x * DIM);
        const float4* eB = (const float4*)(emb + (size_t)cd.y * DIM);

        float n0 = 0.f, n1 = 0.f, n2 = 0.f, n3 = 0.f;
        float a0 = 0.f, a1 = 0.f, a2 = 0.f, a3 = 0.f;
        float b0 = 0.f, b1 = 0.f, b2 = 0.f, b3 = 0.f;
#pragma unroll
        for (int j = 0; j < 16; ++j) {
            float4 xv = xr[j];
            float4 ev = eA[j], fv = eB[j];
            n0 = fmaf(xv.x, xv.x, n0);
            n1 = fmaf(xv.y, xv.y, n1);
            n2 = fmaf(xv.z, xv.z, n2);
            n3 = fmaf(xv.w, xv.w, n3);
            a0 = fmaf(xv.x, ev.x, a0);
            a1 = fmaf(xv.y, ev.y, a1);
            a2 = fmaf(xv.z, ev.z, a2);
            a3 = fmaf(xv.w, ev.w, a3);
            b0 = fmaf(xv.x, fv.x, b0);
            b1 = fmaf(xv.y, fv.y, b1);
            b2 = fmaf(xv.z, fv.z, b2);
            b3 = fmaf(xv.w, fv.w, b3);
        }
        float xn = (n0 + n1) + (n2 + n3);
        float dotA = (a0 + a1) + (a2 + a3);
        float dotB = (b0 + b1) + (b2 + b3);
        float dA = fmaf(-2.f, dotA, xn) + norms[cd.x];
        float dB = fmaf(-2.f, dotB, xn) + norms[cd.y];
        // np.argmin keeps FIRST minimum -> ties to smaller index
        int bi = (dB < dA || (dB == dA && cd.y < cd.x)) ? cd.y : cd.x;

        // err pass: sum (x - e_bi)^2
        const float4* ebv = (const float4*)(emb + (size_t)bi * DIM);
        float c0 = 0.f, c1 = 0.f, c2 = 0.f, c3 = 0.f;
#pragma unroll
        for (int j = 0; j < 16; ++j) {
            float4 xv = xr[j];
            float4 ev = ebv[j];
            float e0 = xv.x - ev.x, e1 = xv.y - ev.y;
            float e2 = xv.z - ev.z, e3 = xv.w - ev.w;
            c0 = fmaf(e0, e0, c0);
            c1 = fmaf(e1, e1, c1);
            c2 = fmaf(e2, e2, c2);
            c3 = fmaf(e3, e3, c3);
        }
        float err = (c0 + c1) + (c2 + c3);

        sbi[tid] = bi;
        serr[tid] = err;
        atomicAdd(&hist[bi], 1u);
        // one-hot into the memset-zeroed region
        enc[(size_t)grow * KCB + bi] = 1.0f;
    }
    __syncthreads();

    // flush histogram
    for (int j = tid; j < KCB; j += 256) {
        unsigned int c = hist[j];
        if (c) atomicAdd(&counts[j], c);
    }
    // loss reduction over 128 row errors
    if (tid < 64) {
        float v = serr[tid] + serr[tid + 64];
#pragma unroll
        for (int off = 32; off > 0; off >>= 1) v += __shfl_down(v, off);
        if (tid == 0) atomicAdd(loss_acc, v);
    }
    // cooperative quantized write (dword stores; qout = out+1, 4B-aligned)
#pragma unroll 4
    for (int j = 0; j < 32; ++j) {
        int f = j * 256 + tid;          // 0..8191
        int r = f >> 6, c = f & 63;
        qout[((size_t)blockIdx.x * 128 + r) * DIM + c] =
            emb[(size_t)sbi[r] * DIM + c];
    }

    // ---- last-block finalization (loss + perplexity)
    __threadfence();
    if (tid == 0) ticket_s = atomicAdd(done, 1u);
    __syncthreads();
    if (ticket_s == 1023u) {
        float* red = (float*)hist;   // reuse LDS (2 KB >= 256 floats)
        unsigned int ca = __hip_atomic_load(&counts[tid], __ATOMIC_RELAXED,
                                            __HIP_MEMORY_SCOPE_AGENT);
        unsigned int cb = __hip_atomic_load(&counts[tid + 256], __ATOMIC_RELAXED,
                                            __HIP_MEMORY_SCOPE_AGENT);
        float pa = (float)ca * (1.0f / 131072.0f);
        float pb = (float)cb * (1.0f / 131072.0f);
        red[tid] = pa * logf(pa + 1e-10f) + pb * logf(pb + 1e-10f);
        __syncthreads();
        for (int s = 128; s > 0; s >>= 1) {
            if (tid < s) red[tid] += red[tid + s];
            __syncthreads();
        }
        if (tid == 0) {
            out[8388609] = expf(-red[0]);
            float lt = __hip_atomic_load(loss_acc, __ATOMIC_RELAXED,
                                         __HIP_MEMORY_SCOPE_AGENT);
            out[0] = 1.25f * lt * (1.0f / 8388608.0f);
        }
    }
}

extern "C" void kernel_launch(void* const* d_in, const int* in_sizes, int n_in,
                              void* d_out, int out_size, void* d_ws, size_t ws_size,
                              hipStream_t stream) {
    const float* x   = (const float*)d_in[0];
    const float* emb = (const float*)d_in[1];
    float* out = (float*)d_out;
    char* ws = (char*)d_ws;
    unsigned int* counts = (unsigned int*)ws;
    float* loss_acc = (float*)(ws + 2048);
    unsigned int* done = (unsigned int*)(ws + 2052);
    float* norms = (float*)(ws + 4096);
    unsigned short* e_bf = (unsigned short*)(ws + 8192);

    // zero the 268 MB encodings region via the runtime's ~7 TB/s fill path
    hipMemsetAsync(out + 8388610, 0, (size_t)NVEC * KCB * sizeof(float), stream);
    vq_prep<<<8, 256, 0, stream>>>(emb, norms, e_bf, counts, loss_acc, done);
    vq_fused<<<1024, 256, 0, stream>>>(x, emb, e_bf, norms, out, counts, loss_acc, done);
}

// Round 10
// 174.783 us; speedup vs baseline: 1.7947x; 1.7947x over previous
//
#include <hip/hip_runtime.h>
#include <math.h>

#define NVEC 131072
#define DIM 64
#define KCB 512
#define FLT_BIG 3.402823466e38f

typedef __attribute__((ext_vector_type(8))) short bf16x8;
typedef __attribute__((ext_vector_type(4))) float f32x4;

// d_out layout (floats): [0] loss | [1..8388608] quantized | [8388609] perplexity
//                        | [8388610 ..] encodings (131072 x 512)
// d_ws layout (bytes):
//   [0,2048)         u32 counts[512]
//   [2048]           float loss_acc
//   [4096,6144)      float norms[512]
//   [8192, +128K)    ushort e_bf[512][128]      (row: eh[64] | el[64])

__device__ inline unsigned int bf16_rne(float f) {
    unsigned int u = __float_as_uint(f);
    u += 0x7fffu + ((u >> 16) & 1u);
    return u >> 16;
}

__device__ inline void split_frag(float4 p0, float4 p1, bf16x8& hi, bf16x8& lo) {
    union { bf16x8 v; unsigned int u[4]; } H, L;
    float f[8] = {p0.x, p0.y, p0.z, p0.w, p1.x, p1.y, p1.z, p1.w};
    unsigned int h[8];
    float r[8];
#pragma unroll
    for (int j = 0; j < 8; ++j) {
        h[j] = bf16_rne(f[j]);
        r[j] = f[j] - __uint_as_float(h[j] << 16);
    }
#pragma unroll
    for (int j = 0; j < 4; ++j) {
        H.u[j] = h[2 * j] | (h[2 * j + 1] << 16);
        L.u[j] = bf16_rne(r[2 * j]) | (bf16_rne(r[2 * j + 1]) << 16);
    }
    hi = H.v;
    lo = L.v;
}

// merge two top-2 lists across lane groups (k-subsets are disjoint)
__device__ inline void merge_top2(float& d1, int& i1, float& d2, int& i2) {
#pragma unroll
    for (int m = 16; m <= 32; m <<= 1) {
        float e1 = __shfl_xor(d1, m), e2 = __shfl_xor(d2, m);
        int j1 = __shfl_xor(i1, m), j2 = __shfl_xor(i2, m);
        bool af = (d1 < e1) || (d1 == e1 && i1 < j1);
        float w2 = af ? d2 : e2; int w2i = af ? i2 : j2;   // winner's runner-up
        float lb = af ? e1 : d1; int lbi = af ? j1 : i1;   // loser's best
        bool bs = (w2 < lb) || (w2 == lb && w2i < lbi);
        d1 = af ? d1 : e1; i1 = af ? i1 : j1;
        d2 = bs ? w2 : lb; i2 = bs ? w2i : lbi;
    }
}

// prep: norms (fp32), bf16 hi/lo codebook, zero counts/loss
__global__ __launch_bounds__(256) void vq_prep(const float* __restrict__ emb,
                                               float* __restrict__ norms,
                                               unsigned short* __restrict__ e_bf,
                                               unsigned int* __restrict__ counts,
                                               float* __restrict__ loss_acc) {
    int gid = blockIdx.x * 256 + threadIdx.x;   // 0..2047
    int row = gid >> 2, part = gid & 3, d0 = part * 16;
    const float* e = emb + row * DIM + d0;
    float s = 0.f;
#pragma unroll
    for (int d = 0; d < 16; ++d) s = fmaf(e[d], e[d], s);
    s += __shfl_xor(s, 1);
    s += __shfl_xor(s, 2);
    if (part == 0) norms[row] = s;
#pragma unroll
    for (int d = 0; d < 16; ++d) {
        float f = e[d];
        unsigned int h = bf16_rne(f);
        float r = f - __uint_as_float(h << 16);
        e_bf[row * 128 + d0 + d] = (unsigned short)h;
        e_bf[row * 128 + 64 + d0 + d] = (unsigned short)bf16_rne(r);
    }
    if (gid < KCB) counts[gid] = 0u;
    if (gid == 0) *loss_acc = 0.f;
}

// fused: MFMA top-2 argmin, exact fp32 rescore, loss, histogram,
// quantized + one-hot writes. (encodings region pre-zeroed by hipMemsetAsync;
// NO device-scope fences here — they serialize L2 writebacks per block.)
__global__ __launch_bounds__(256) void vq_fused(const float* __restrict__ x,
                                                const float* __restrict__ emb,
                                                const unsigned short* __restrict__ e_bf,
                                                const float* __restrict__ norms,
                                                float* __restrict__ out,
                                                unsigned int* __restrict__ counts,
                                                float* __restrict__ loss_acc) {
    float* __restrict__ qout = out + 1;
    float* __restrict__ enc  = out + 8388610;
    int tid = threadIdx.x;
    int wave = tid >> 6;
    int lane = tid & 63;
    int nl = lane & 15, kg = lane >> 4;
    int rowA = blockIdx.x * 128 + wave * 32 + nl;
    int rowB = rowA + 16;

    __shared__ unsigned int hist[KCB];
    __shared__ int2 scand[128];
    __shared__ int sbi[128];
    __shared__ float serr[128];
    for (int j = tid; j < KCB; j += 256) hist[j] = 0u;

    // B-frags (x side): lane col = x-row, k = kg*8+e (+32 per kslice)
    bf16x8 xhA[2], xlA[2], xhB[2], xlB[2];
    {
        const float* xA = x + (size_t)rowA * DIM;
        const float* xB = x + (size_t)rowB * DIM;
#pragma unroll
        for (int ks = 0; ks < 2; ++ks) {
            const float4* pA = (const float4*)(xA + ks * 32 + kg * 8);
            const float4* pB = (const float4*)(xB + ks * 32 + kg * 8);
            split_frag(pA[0], pA[1], xhA[ks], xlA[ks]);
            split_frag(pB[0], pB[1], xhB[ks], xlB[ks]);
        }
    }

    float d1A = FLT_BIG, d2A = FLT_BIG, d1B = FLT_BIG, d2B = FLT_BIG;
    int i1A = 0, i2A = 0, i1B = 0, i2B = 0;

    const unsigned short* ebl = e_bf + (size_t)nl * 128;
#pragma unroll 2
    for (int t = 0; t < 32; ++t) {
        const unsigned short* eb = ebl + t * 2048;  // codebook row t*16+nl
        bf16x8 eh0 = *(const bf16x8*)(eb + kg * 8);
        bf16x8 eh1 = *(const bf16x8*)(eb + 32 + kg * 8);
        bf16x8 el0 = *(const bf16x8*)(eb + 64 + kg * 8);
        bf16x8 el1 = *(const bf16x8*)(eb + 96 + kg * 8);

        f32x4 aA = {}, aB = {};
        // dot = xh*eh + xh*el + xl*eh  (A = e-side, B = x-side)
        aA = __builtin_amdgcn_mfma_f32_16x16x32_bf16(eh0, xhA[0], aA, 0, 0, 0);
        aA = __builtin_amdgcn_mfma_f32_16x16x32_bf16(eh1, xhA[1], aA, 0, 0, 0);
        aA = __builtin_amdgcn_mfma_f32_16x16x32_bf16(el0, xhA[0], aA, 0, 0, 0);
        aA = __builtin_amdgcn_mfma_f32_16x16x32_bf16(el1, xhA[1], aA, 0, 0, 0);
        aA = __builtin_amdgcn_mfma_f32_16x16x32_bf16(eh0, xlA[0], aA, 0, 0, 0);
        aA = __builtin_amdgcn_mfma_f32_16x16x32_bf16(eh1, xlA[1], aA, 0, 0, 0);

        aB = __builtin_amdgcn_mfma_f32_16x16x32_bf16(eh0, xhB[0], aB, 0, 0, 0);
        aB = __builtin_amdgcn_mfma_f32_16x16x32_bf16(eh1, xhB[1], aB, 0, 0, 0);
        aB = __builtin_amdgcn_mfma_f32_16x16x32_bf16(el0, xhB[0], aB, 0, 0, 0);
        aB = __builtin_amdgcn_mfma_f32_16x16x32_bf16(el1, xhB[1], aB, 0, 0, 0);
        aB = __builtin_amdgcn_mfma_f32_16x16x32_bf16(eh0, xlB[0], aB, 0, 0, 0);
        aB = __builtin_amdgcn_mfma_f32_16x16x32_bf16(eh1, xlB[1], aB, 0, 0, 0);

        // C/D: col=lane&15 (x-row), row=(lane>>4)*4+reg (e-idx) [m89-verified]
        int krow0 = t * 16 + kg * 4;
#pragma unroll
        for (int r = 0; r < 4; ++r) {
            float en = norms[krow0 + r];
            int ki = krow0 + r;
            float dA = fmaf(-2.f, aA[r], en);   // xn dropped: row-constant
            bool c1 = dA < d1A, c2 = dA < d2A;
            d2A = c1 ? d1A : (c2 ? dA : d2A);
            i2A = c1 ? i1A : (c2 ? ki : i2A);
            d1A = c1 ? dA : d1A;
            i1A = c1 ? ki : i1A;
            float dB = fmaf(-2.f, aB[r], en);
            bool e1c = dB < d1B, e2c = dB < d2B;
            d2B = e1c ? d1B : (e2c ? dB : d2B);
            i2B = e1c ? i1B : (e2c ? ki : i2B);
            d1B = e1c ? dB : d1B;
            i1B = e1c ? ki : i1B;
        }
    }

    merge_top2(d1A, i1A, d2A, i2A);
    merge_top2(d1B, i1B, d2B, i2B);
    if (lane < 16) {
        scand[wave * 32 + nl] = make_int2(i1A, i2A);
        scand[wave * 32 + nl + 16] = make_int2(i1B, i2B);
    }
    __syncthreads();

    // ---- exact fp32 rescore: one thread per row, STREAMED (low VGPR)
    if (tid < 128) {
        int grow = blockIdx.x * 128 + tid;
        int2 cd = scand[tid];
        const float4* xr = (const float4*)(x + (size_t)grow * DIM);
        const float4* eA = (const float4*)(emb + (size_t)cd.x * DIM);
        const float4* eB = (const float4*)(emb + (size_t)cd.y * DIM);

        float n0 = 0.f, n1 = 0.f, n2 = 0.f, n3 = 0.f;
        float a0 = 0.f, a1 = 0.f, a2 = 0.f, a3 = 0.f;
        float b0 = 0.f, b1 = 0.f, b2 = 0.f, b3 = 0.f;
#pragma unroll
        for (int j = 0; j < 16; ++j) {
            float4 xv = xr[j];
            float4 ev = eA[j], fv = eB[j];
            n0 = fmaf(xv.x, xv.x, n0);
            n1 = fmaf(xv.y, xv.y, n1);
            n2 = fmaf(xv.z, xv.z, n2);
            n3 = fmaf(xv.w, xv.w, n3);
            a0 = fmaf(xv.x, ev.x, a0);
            a1 = fmaf(xv.y, ev.y, a1);
            a2 = fmaf(xv.z, ev.z, a2);
            a3 = fmaf(xv.w, ev.w, a3);
            b0 = fmaf(xv.x, fv.x, b0);
            b1 = fmaf(xv.y, fv.y, b1);
            b2 = fmaf(xv.z, fv.z, b2);
            b3 = fmaf(xv.w, fv.w, b3);
        }
        float xn = (n0 + n1) + (n2 + n3);
        float dotA = (a0 + a1) + (a2 + a3);
        float dotB = (b0 + b1) + (b2 + b3);
        float dA = fmaf(-2.f, dotA, xn) + norms[cd.x];
        float dB = fmaf(-2.f, dotB, xn) + norms[cd.y];
        // np.argmin keeps FIRST minimum -> ties to smaller index
        int bi = (dB < dA || (dB == dA && cd.y < cd.x)) ? cd.y : cd.x;

        // err pass: sum (x - e_bi)^2
        const float4* ebv = (const float4*)(emb + (size_t)bi * DIM);
        float c0 = 0.f, c1 = 0.f, c2 = 0.f, c3 = 0.f;
#pragma unroll
        for (int j = 0; j < 16; ++j) {
            float4 xv = xr[j];
            float4 ev = ebv[j];
            float e0 = xv.x - ev.x, e1 = xv.y - ev.y;
            float e2 = xv.z - ev.z, e3 = xv.w - ev.w;
            c0 = fmaf(e0, e0, c0);
            c1 = fmaf(e1, e1, c1);
            c2 = fmaf(e2, e2, c2);
            c3 = fmaf(e3, e3, c3);
        }
        float err = (c0 + c1) + (c2 + c3);

        sbi[tid] = bi;
        serr[tid] = err;
        atomicAdd(&hist[bi], 1u);
        // one-hot into the memset-zeroed region
        enc[(size_t)grow * KCB + bi] = 1.0f;
    }
    __syncthreads();

    // flush histogram
    for (int j = tid; j < KCB; j += 256) {
        unsigned int c = hist[j];
        if (c) atomicAdd(&counts[j], c);
    }
    // loss reduction over 128 row errors
    if (tid < 64) {
        float v = serr[tid] + serr[tid + 64];
#pragma unroll
        for (int off = 32; off > 0; off >>= 1) v += __shfl_down(v, off);
        if (tid == 0) atomicAdd(loss_acc, v);
    }
    // cooperative quantized write (dword stores; qout = out+1, 4B-aligned)
#pragma unroll 4
    for (int j = 0; j < 32; ++j) {
        int f = j * 256 + tid;          // 0..8191
        int r = f >> 6, c = f & 63;
        qout[((size_t)blockIdx.x * 128 + r) * DIM + c] =
            emb[(size_t)sbi[r] * DIM + c];
    }
}

__global__ __launch_bounds__(512) void vq_final(const unsigned int* __restrict__ counts,
                                                const float* __restrict__ loss_acc,
                                                float* __restrict__ out) {
    __shared__ float red[512];
    int t = threadIdx.x;
    float p = (float)counts[t] * (1.0f / 131072.0f);
    red[t] = p * logf(p + 1e-10f);
    __syncthreads();
    for (int s = 256; s > 0; s >>= 1) {
        if (t < s) red[t] += red[t + s];
        __syncthreads();
    }
    if (t == 0) {
        out[8388609] = expf(-red[0]);
        out[0] = 1.25f * (*loss_acc) * (1.0f / 8388608.0f);
    }
}

extern "C" void kernel_launch(void* const* d_in, const int* in_sizes, int n_in,
                              void* d_out, int out_size, void* d_ws, size_t ws_size,
                              hipStream_t stream) {
    const float* x   = (const float*)d_in[0];
    const float* emb = (const float*)d_in[1];
    float* out = (float*)d_out;
    char* ws = (char*)d_ws;
    unsigned int* counts = (unsigned int*)ws;
    float* loss_acc = (float*)(ws + 2048);
    float* norms = (float*)(ws + 4096);
    unsigned short* e_bf = (unsigned short*)(ws + 8192);

    // zero the 268 MB encodings region via the runtime's ~7 TB/s fill path
    hipMemsetAsync(out + 8388610, 0, (size_t)NVEC * KCB * sizeof(float), stream);
    vq_prep<<<8, 256, 0, stream>>>(emb, norms, e_bf, counts, loss_acc);
    vq_fused<<<1024, 256, 0, stream>>>(x, emb, e_bf, norms, out, counts, loss_acc);
    vq_final<<<1, 512, 0, stream>>>(counts, loss_acc, out);
}